// Round 9
// baseline (537.009 us; speedup 1.0000x reference)
//
#include <hip/hip_runtime.h>
#include <math.h>

#define FIELD 2097152   // 32*512*128
#define NSEQ  4096      // 32*128 sequences

typedef float f2 __attribute__((ext_vector_type(2)));   // (re, im) -> VGPR pair

__device__ __forceinline__ f2 cmuli(f2 a)  { return (f2){-a.y, a.x}; }  //  i*a
__device__ __forceinline__ f2 cmulni(f2 a) { return (f2){a.y, -a.x}; }  // -i*a
__device__ __forceinline__ f2 conjf2(f2 a) { return (f2){a.x, -a.y}; }
__device__ __forceinline__ f2 cmul(f2 a, float c, float s) {   // a*(c+is)
  return c * a + s * cmuli(a);
}
__device__ __forceinline__ f2 cmulc(f2 a, float c, float s) {  // a*(c-is)
  return c * a - s * cmuli(a);
}
__device__ __forceinline__ f2 shflx2(f2 v, int h) {
  return (f2){__shfl_xor(v.x, h, 64), __shfl_xor(v.y, h, 64)};
}
__device__ __forceinline__ f2 shfl2(f2 v, int l) {
  return (f2){__shfl(v.x, l, 64), __shfl(v.y, l, 64)};
}

// DFT4 over the lane's 4 register slots (packed complex).
__device__ __forceinline__ void fft4_fwd(f2* v) {
  f2 t0 = v[0] + v[2], t1 = v[0] - v[2];
  f2 t2 = v[1] + v[3], t3 = v[1] - v[3];
  v[0] = t0 + t2; v[2] = t0 - t2;
  v[1] = t1 + cmulni(t3);
  v[3] = t1 + cmuli(t3);
}
__device__ __forceinline__ void fft4_inv(f2* v) {
  f2 t0 = v[0] + v[2], t1 = v[0] - v[2];
  f2 t2 = v[1] + v[3], t3 = v[1] - v[3];
  v[0] = t0 + t2; v[2] = t0 - t2;
  v[1] = t1 + cmuli(t3);
  v[3] = t1 + cmulni(t3);
}

// 256-point FFT: time n = 64a+lane (slot a) <-> freq k = 4*rev6(lane)+b.
__device__ __forceinline__ void fft256_fwd(f2* v,
                                           const float* twFr, const float* twFi,
                                           const float* Wr, const float* Wi,
                                           int lane) {
  fft4_fwd(v);
#pragma unroll
  for (int b = 1; b < 4; ++b) v[b] = cmul(v[b], twFr[b-1], twFi[b-1]);
#pragma unroll
  for (int s = 0; s < 6; ++s) {
    const int h = 32 >> s;
    const bool hi = (lane & h) != 0;
    const float sg = hi ? -1.0f : 1.0f;
#pragma unroll
    for (int b = 0; b < 4; ++b) {
      f2 p = shflx2(v[b], h);
      f2 t = sg * v[b] + p;
      f2 m = cmul(t, Wr[s], Wi[s]);
      v[b] = hi ? m : t;
    }
  }
}

__device__ __forceinline__ void ifft256(f2* v,
                                        const float* twFr, const float* twFi,
                                        const float* Wr, const float* Wi,
                                        int lane) {
#pragma unroll
  for (int s = 5; s >= 0; --s) {
    const int h = 32 >> s;
    const bool hi = (lane & h) != 0;
    const float sg = hi ? -1.0f : 1.0f;
#pragma unroll
    for (int b = 0; b < 4; ++b) {
      f2 p = shflx2(v[b], h);
      f2 q = hi ? v[b] : p;     // operand multiplied by conj(W)
      f2 r = hi ? p : v[b];     // operand added
      f2 t = cmulc(q, Wr[s], Wi[s]);
      v[b] = sg * t + r;
    }
  }
#pragma unroll
  for (int b = 1; b < 4; ++b) v[b] = cmulc(v[b], twFr[b-1], twFi[b-1]);
  fft4_inv(v);
}

// Half-spectrum S[0..255] (+ real scalar S256) -> packed Z for ifft256.
__device__ __forceinline__ void half_to_z(f2* S, float S256,
                                          const float* twHr, const float* twHi,
                                          int lane, int pl0, int plx) {
  f2 P[4];
  P[0] = shfl2(S[0], pl0);
#pragma unroll
  for (int b = 1; b < 4; ++b) P[b] = shfl2(S[4 - b], plx);
  P[0] = (lane == 0) ? (f2){S256, 0.0f} : P[0];
#pragma unroll
  for (int b = 0; b < 4; ++b) {
    f2 cP = conjf2(P[b]);
    f2 A = 0.5f * (S[b] + cP);
    f2 B = 0.5f * (S[b] - cP);
    f2 Bt = cmul(B, twHr[b], twHi[b]);
    S[b] = A + cmuli(Bt);
  }
}

// Per-bin mode update exploiting Hermitian symmetry (no cross-lane ops).
__device__ __forceinline__ void mode_update4(const f2* X, const f2* V, f2* U,
                                             const float* lam1, const float* lam2,
                                             float om, float f0) {
#pragma unroll
  for (int b = 0; b < 4; ++b) {
    float f = f0 + (float)b * (1.0f / 512.0f);
    float dfp = f - om;
    float dfm = f + om;
    float gp = __builtin_amdgcn_rcpf(fmaf(1600.0f * dfp, dfp, 1.0f));
    float gm = __builtin_amdgcn_rcpf(fmaf(1600.0f * dfm, dfm, 1.0f));
    float gs = 0.5f * (gp + gm);
    f2 D = X[b] - V[b];
    float lt = 0.25f * fmaf(lam1[b], gp, lam2[b] * gm);
    U[b] = gs * D + (f2){lt, 0.0f};
  }
}

// One wave per (b,d) sequence; half-spectrum, packed-f32 complex math.
// waves_per_eu(5,5): 20 waves/CU = 5 blocks/CU -> 1280 resident slots for
// 1024 blocks (whole grid in ONE pass, no tail) AND a ~96-VGPR budget that
// exceeds demand (~80) so the allocator stops spilling (rounds 6-8 at (4,4)
// chose 64 VGPRs and leaked ~43 MB/launch of scratch traffic).
__global__ __attribute__((amdgpu_flat_work_group_size(256, 256),
                          amdgpu_waves_per_eu(5, 5)))
void vmd_kernel(const float* __restrict__ x, float* __restrict__ out) {
  __shared__ float stage[4 * 512];    // [seq][n]; x resident during loop, reused for out
  __shared__ float ldsLam[4 * 512];   // psi-permuted lambda per wave

  const int tid = threadIdx.x;
  const int wv = tid >> 6;
  const int lane = tid & 63;
  const int w = (blockIdx.x >> 3) + ((blockIdx.x & 7) << 7);   // XCD swizzle
  const int g = 4 * w + wv;
  const int bb = w >> 5;
  const int d0 = (4 * w) & 127;
  const int base4 = bb * 16384 + (d0 >> 2);
  float* lamLds = ldsLam + wv * 512;
  f2* stg2 = (f2*)stage + wv * 256;   // packed (even,odd) pair view of this seq

  const int rev = (int)(__brev((unsigned)lane) >> 26);           // rev6(lane)
  const float f0 = (float)rev * (1.0f / 128.0f);
  const int plx = lane ^ 63;
  const int pl0 = (int)(__brev((unsigned)((64 - rev) & 63)) >> 26);

  float Wr[6], Wi[6];
#pragma unroll
  for (int s = 0; s < 6; ++s) {
    const int h = 32 >> s;
    float th = (float)(lane & (h - 1)) * (3.14159265358979323846f / (float)h);
    float sn, cs; sincosf(th, &sn, &cs);
    Wr[s] = cs; Wi[s] = -sn;
  }
  float twFr[3], twFi[3];
#pragma unroll
  for (int b = 1; b < 4; ++b) {
    float th = (float)(lane * b) * 0.02454369260617026f;   // 2pi/256
    float sn, cs; sincosf(th, &sn, &cs);
    twFr[b-1] = cs; twFi[b-1] = -sn;
  }
  float twHr[4], twHi[4];
#pragma unroll
  for (int b = 0; b < 4; ++b) {
    float th = (float)(4 * rev + b) * 0.01227184630308513f; // 2pi/512
    float sn, cs; sincosf(th, &sn, &cs);
    twHr[b] = cs; twHi[b] = sn;
  }

  // ---- load x: float4 (n, d0..d0+3) -> stage[seq][n]; zero lambda ----
  {
    const float4* x4 = (const float4*)x;
    float4 va = x4[base4 + tid * 32];
    float4 vb = x4[base4 + (tid + 256) * 32];
    stage[tid]        = va.x; stage[512 + tid]        = va.y;
    stage[1024 + tid] = va.z; stage[1536 + tid]       = va.w;
    stage[tid + 256]        = vb.x; stage[512 + tid + 256]  = vb.y;
    stage[1024 + tid + 256] = vb.z; stage[1536 + tid + 256] = vb.w;
#pragma unroll
    for (int j = 0; j < 8; ++j) ldsLam[tid * 8 + j] = 0.0f;
  }
  __syncthreads();

  // ---- initial FFT input straight from LDS (x stays resident in stage) ----
  f2 z[4];
#pragma unroll
  for (int a = 0; a < 4; ++a) z[a] = stg2[64 * a + lane];
  fft256_fwd(z, twFr, twFi, Wr, Wi, lane);
  f2 X[4];
  float X256;
  {
    f2 P[4];
    P[0] = shfl2(z[0], pl0);
#pragma unroll
    for (int b = 1; b < 4; ++b) P[b] = shfl2(z[4 - b], plx);
    X256 = __shfl(z[0].x - z[0].y, 0, 64);
#pragma unroll
    for (int b = 0; b < 4; ++b) {
      f2 cP = conjf2(P[b]);
      f2 E = 0.5f * (z[b] + cP);
      f2 O = 0.5f * cmulni(z[b] - cP);
      X[b] = E + cmulc(O, twHr[b], twHi[b]);
    }
  }

  f2 U0[4], U1[4], lam[4];
#pragma unroll
  for (int b = 0; b < 4; ++b) {
    U0[b] = (f2){0.0f, 0.0f}; U1[b] = (f2){0.0f, 0.0f};
    lam[b] = (f2){0.0f, 0.0f};
  }
  float U0_256 = 0.0f, U1_256 = 0.0f;
  float om0 = 0.0f, om1 = 0.0f;

  const int psiE = 256 * (lane & 1) + (lane >> 1);   // lambda write base

#pragma unroll 1
  for (int it = 0; it < 50; ++it) {
    // lambda reads (psi layout): lam1[b]=lam[k+256], lam2[b]=lam[256-k]
    float lam1[4], lam2[4];
#pragma unroll
    for (int b = 0; b < 4; ++b) lam1[b] = lamLds[128 * b + 64 + rev];
    lam2[0] = lamLds[64 - rev];
#pragma unroll
    for (int b = 1; b < 4; ++b) lam2[b] = lamLds[128 * (4 - b) + 63 - rev];
    float lam0 = lamLds[0];

    mode_update4(X, U1, U0, lam1, lam2, om0, f0);
    {
      float dm = 0.5f + om0;
      float gg = __builtin_amdgcn_rcpf(fmaf(1600.0f * dm, dm, 1.0f));
      U0_256 = (X256 - U1_256 + 0.5f * lam0) * gg;
    }
    mode_update4(X, U0, U1, lam1, lam2, om1, f0);
    {
      float dm = 0.5f + om1;
      float gg = __builtin_amdgcn_rcpf(fmaf(1600.0f * dm, dm, 1.0f));
      U1_256 = (X256 - U0_256 + 0.5f * lam0) * gg;
    }

    // omega: all stored bins are positive freqs
    float n0 = 0.0f, d0s = 0.0f, n1 = 0.0f, d1 = 0.0f;
#pragma unroll
    for (int b = 0; b < 4; ++b) {
      float f = f0 + (float)b * (1.0f / 512.0f);
      float p0 = fmaf(U0[b].x, U0[b].x, U0[b].y * U0[b].y);
      float p1 = fmaf(U1[b].x, U1[b].x, U1[b].y * U1[b].y);
      n0 = fmaf(f, p0, n0); d0s += p0;
      n1 = fmaf(f, p1, n1); d1 += p1;
    }
#pragma unroll
    for (int off = 32; off >= 1; off >>= 1) {
      n0 += __shfl_xor(n0, off, 64);
      d0s += __shfl_xor(d0s, off, 64);
      n1 += __shfl_xor(n1, off, 64);
      d1 += __shfl_xor(d1, off, 64);
    }
    om0 = n0 / (d0s + 1e-7f);
    om1 = n1 / (d1 + 1e-7f);

    if (it < 49) {   // last iteration's lambda is never consumed
#pragma unroll
      for (int b = 0; b < 4; ++b) z[b] = U0[b] + U1[b];
      float S256 = U0_256 + U1_256;
      half_to_z(z, S256, twHr, twHi, lane, pl0, plx);
      ifft256(z, twFr, twFi, Wr, Wi, lane);
#pragma unroll
      for (int a = 0; a < 4; ++a) {
        f2 xa = stg2[64 * a + lane];               // x from LDS (saves 8 VGPRs)
        lam[a] = lam[a] + 0.001f * (xa - z[a] * (1.0f / 256.0f));
        lamLds[psiE + 32 * a]       = lam[a].x;
        lamLds[psiE + 32 * a + 128] = lam[a].y;
      }
      asm volatile("s_waitcnt lgkmcnt(0)" ::: "memory");
    }
  }

  // ---- final modes: half->z, ifft256, pack to stage, float4 stores ----
  float4* o4 = (float4*)out;
#pragma unroll
  for (int b = 0; b < 4; ++b) z[b] = U0[b];
  half_to_z(z, U0_256, twHr, twHi, lane, pl0, plx);
  ifft256(z, twFr, twFi, Wr, Wi, lane);
  __syncthreads();   // all waves done reading x from stage
#pragma unroll
  for (int a = 0; a < 4; ++a) stg2[64 * a + lane] = z[a] * (1.0f / 256.0f);
  __syncthreads();
#pragma unroll
  for (int r = 0; r < 2; ++r) {
    const int n = tid + r * 256;
    float4 v;
    v.x = stage[n]; v.y = stage[512 + n]; v.z = stage[1024 + n]; v.w = stage[1536 + n];
    o4[FIELD / 4 + base4 + n * 32] = v;
  }
  __syncthreads();
#pragma unroll
  for (int b = 0; b < 4; ++b) z[b] = U1[b];
  half_to_z(z, U1_256, twHr, twHi, lane, pl0, plx);
  ifft256(z, twFr, twFi, Wr, Wi, lane);
#pragma unroll
  for (int a = 0; a < 4; ++a) stg2[64 * a + lane] = z[a] * (1.0f / 256.0f);
  __syncthreads();
#pragma unroll
  for (int r = 0; r < 2; ++r) {
    const int n = tid + r * 256;
    float4 v;
    v.x = stage[n]; v.y = stage[512 + n]; v.z = stage[1024 + n]; v.w = stage[1536 + n];
    o4[2 * FIELD / 4 + base4 + n * 32] = v;
  }

  if (lane == 0) {
    out[g] = om0;            // staged in trend region (zeroed later)
    out[NSEQ + g] = om1;
  }
}

__global__ __launch_bounds__(128) void order_kernel(float* __restrict__ out) {
  const int bb = blockIdx.x;
  const int dd = threadIdx.x;
  float o0 = out[bb * 128 + dd];
  float o1 = out[NSEQ + bb * 128 + dd];
#pragma unroll
  for (int off = 32; off >= 1; off >>= 1) {
    o0 += __shfl_down(o0, off);
    o1 += __shfl_down(o1, off);
  }
  __shared__ float s0[2], s1[2];
  const int wv = dd >> 6;
  if ((dd & 63) == 0) { s0[wv] = o0; s1[wv] = o1; }
  __syncthreads();
  if (dd == 0) {
    const float a = s0[0] + s0[1];
    const float c = s1[0] + s1[1];
    out[2 * NSEQ + bb] = (a > c) ? 1.0f : 0.0f;
  }
}

__global__ __launch_bounds__(256) void swap_kernel(float* __restrict__ out) {
  const int idx = blockIdx.x * 256 + threadIdx.x;
  const int bb = idx >> 16;
  const float flag = out[2 * NSEQ + bb];
  if (flag > 0.5f) {
    const float p = out[FIELD + idx];
    const float r = out[2 * FIELD + idx];
    out[FIELD + idx] = r;
    out[2 * FIELD + idx] = p;
  }
}

extern "C" void kernel_launch(void* const* d_in, const int* in_sizes, int n_in,
                              void* d_out, int out_size, void* d_ws, size_t ws_size,
                              hipStream_t stream) {
  (void)in_sizes; (void)n_in; (void)d_ws; (void)ws_size; (void)out_size;
  const float* x = (const float*)d_in[0];
  float* out = (float*)d_out;
  vmd_kernel<<<NSEQ / 4, 256, 0, stream>>>(x, out);
  order_kernel<<<32, 128, 0, stream>>>(out);
  swap_kernel<<<FIELD / 256, 256, 0, stream>>>(out);
  hipMemsetAsync(out, 0, (size_t)FIELD * sizeof(float), stream);
}

// Round 10
// 325.557 us; speedup vs baseline: 1.6495x; 1.6495x over previous
//
#include <hip/hip_runtime.h>
#include <math.h>

#define FIELD 2097152   // 32*512*128
#define NSEQ  4096      // 32*128 sequences

typedef float f2 __attribute__((ext_vector_type(2)));   // (re, im) -> VGPR pair

__device__ __forceinline__ f2 cmuli(f2 a)  { return (f2){-a.y, a.x}; }  //  i*a
__device__ __forceinline__ f2 cmulni(f2 a) { return (f2){a.y, -a.x}; }  // -i*a
__device__ __forceinline__ f2 conjf2(f2 a) { return (f2){a.x, -a.y}; }
__device__ __forceinline__ f2 cmul(f2 a, float c, float s) {   // a*(c+is)
  return c * a + s * cmuli(a);
}
__device__ __forceinline__ f2 cmulc(f2 a, float c, float s) {  // a*(c-is)
  return c * a - s * cmuli(a);
}
__device__ __forceinline__ f2 shflx2(f2 v, int h) {
  return (f2){__shfl_xor(v.x, h, 64), __shfl_xor(v.y, h, 64)};
}
__device__ __forceinline__ f2 shfl2(f2 v, int l) {
  return (f2){__shfl(v.x, l, 64), __shfl(v.y, l, 64)};
}

// DFT4 over the lane's 4 register slots (packed complex).
__device__ __forceinline__ void fft4_fwd(f2* v) {
  f2 t0 = v[0] + v[2], t1 = v[0] - v[2];
  f2 t2 = v[1] + v[3], t3 = v[1] - v[3];
  v[0] = t0 + t2; v[2] = t0 - t2;
  v[1] = t1 + cmulni(t3);
  v[3] = t1 + cmuli(t3);
}
__device__ __forceinline__ void fft4_inv(f2* v) {
  f2 t0 = v[0] + v[2], t1 = v[0] - v[2];
  f2 t2 = v[1] + v[3], t3 = v[1] - v[3];
  v[0] = t0 + t2; v[2] = t0 - t2;
  v[1] = t1 + cmuli(t3);
  v[3] = t1 + cmulni(t3);
}

// 256-point FFT: time n = 64a+lane (slot a) <-> freq k = 4*rev6(lane)+b.
__device__ __forceinline__ void fft256_fwd(f2* v,
                                           const float* twFr, const float* twFi,
                                           const float* Wr, const float* Wi,
                                           int lane) {
  fft4_fwd(v);
#pragma unroll
  for (int b = 1; b < 4; ++b) v[b] = cmul(v[b], twFr[b-1], twFi[b-1]);
#pragma unroll
  for (int s = 0; s < 6; ++s) {
    const int h = 32 >> s;
    const bool hi = (lane & h) != 0;
    const float sg = hi ? -1.0f : 1.0f;
#pragma unroll
    for (int b = 0; b < 4; ++b) {
      f2 p = shflx2(v[b], h);
      f2 t = sg * v[b] + p;
      f2 m = cmul(t, Wr[s], Wi[s]);
      v[b] = hi ? m : t;
    }
  }
}

__device__ __forceinline__ void ifft256(f2* v,
                                        const float* twFr, const float* twFi,
                                        const float* Wr, const float* Wi,
                                        int lane) {
#pragma unroll
  for (int s = 5; s >= 0; --s) {
    const int h = 32 >> s;
    const bool hi = (lane & h) != 0;
    const float sg = hi ? -1.0f : 1.0f;
#pragma unroll
    for (int b = 0; b < 4; ++b) {
      f2 p = shflx2(v[b], h);
      f2 q = hi ? v[b] : p;     // operand multiplied by conj(W)
      f2 r = hi ? p : v[b];     // operand added
      f2 t = cmulc(q, Wr[s], Wi[s]);
      v[b] = sg * t + r;
    }
  }
#pragma unroll
  for (int b = 1; b < 4; ++b) v[b] = cmulc(v[b], twFr[b-1], twFi[b-1]);
  fft4_inv(v);
}

// Half-spectrum S[0..255] (+ real scalar S256) -> packed Z for ifft256.
__device__ __forceinline__ void half_to_z(f2* S, float S256,
                                          const float* twHr, const float* twHi,
                                          int lane, int pl0, int plx) {
  f2 P[4];
  P[0] = shfl2(S[0], pl0);
#pragma unroll
  for (int b = 1; b < 4; ++b) P[b] = shfl2(S[4 - b], plx);
  P[0] = (lane == 0) ? (f2){S256, 0.0f} : P[0];
#pragma unroll
  for (int b = 0; b < 4; ++b) {
    f2 cP = conjf2(P[b]);
    f2 A = 0.5f * (S[b] + cP);
    f2 B = 0.5f * (S[b] - cP);
    f2 Bt = cmul(B, twHr[b], twHi[b]);
    S[b] = A + cmuli(Bt);
  }
}

// Per-bin mode update exploiting Hermitian symmetry (no cross-lane ops).
__device__ __forceinline__ void mode_update4(const f2* X, const f2* V, f2* U,
                                             const float* lam1, const float* lam2,
                                             float om, float f0) {
#pragma unroll
  for (int b = 0; b < 4; ++b) {
    float f = f0 + (float)b * (1.0f / 512.0f);
    float dfp = f - om;
    float dfm = f + om;
    float gp = __builtin_amdgcn_rcpf(fmaf(1600.0f * dfp, dfp, 1.0f));
    float gm = __builtin_amdgcn_rcpf(fmaf(1600.0f * dfm, dfm, 1.0f));
    float gs = 0.5f * (gp + gm);
    f2 D = X[b] - V[b];
    float lt = 0.25f * fmaf(lam1[b], gp, lam2[b] * gm);
    U[b] = gs * D + (f2){lt, 0.0f};
  }
}

// One wave per (b,d) sequence; half-spectrum, packed-f32 complex math.
// amdgpu_num_vgpr(96): EXPLICIT register budget. Rounds 4-9 showed the
// scheduler's pre-RA pressure estimate (not waves_per_eu) sets the RA target:
// (256,3)->84, (3,3)->80, (4,4)->64, (5,5)->48 VGPRs — each below true demand
// (~88), each spilling the difference to scratch (up to 1.3 GB/launch HBM).
// num_vgpr(96) >= demand kills the spill; waves_per_eu(4,4) keeps the
// one-pass residency (1024 blocks = 4 blocks/CU x 256 CU).
__global__ __attribute__((amdgpu_flat_work_group_size(256, 256),
                          amdgpu_waves_per_eu(4, 4),
                          amdgpu_num_vgpr(96)))
void vmd_kernel(const float* __restrict__ x, float* __restrict__ out) {
  __shared__ float stage[4 * 512];    // [seq][n]; x resident during loop, reused for out
  __shared__ float ldsLam[4 * 512];   // psi-permuted lambda per wave

  const int tid = threadIdx.x;
  const int wv = tid >> 6;
  const int lane = tid & 63;
  const int w = (blockIdx.x >> 3) + ((blockIdx.x & 7) << 7);   // XCD swizzle
  const int g = 4 * w + wv;
  const int bb = w >> 5;
  const int d0 = (4 * w) & 127;
  const int base4 = bb * 16384 + (d0 >> 2);
  float* lamLds = ldsLam + wv * 512;
  f2* stg2 = (f2*)stage + wv * 256;   // packed (even,odd) pair view of this seq

  const int rev = (int)(__brev((unsigned)lane) >> 26);           // rev6(lane)
  const float f0 = (float)rev * (1.0f / 128.0f);
  const int plx = lane ^ 63;
  const int pl0 = (int)(__brev((unsigned)((64 - rev) & 63)) >> 26);

  float Wr[6], Wi[6];
#pragma unroll
  for (int s = 0; s < 6; ++s) {
    const int h = 32 >> s;
    float th = (float)(lane & (h - 1)) * (3.14159265358979323846f / (float)h);
    float sn, cs; sincosf(th, &sn, &cs);
    Wr[s] = cs; Wi[s] = -sn;
  }
  float twFr[3], twFi[3];
#pragma unroll
  for (int b = 1; b < 4; ++b) {
    float th = (float)(lane * b) * 0.02454369260617026f;   // 2pi/256
    float sn, cs; sincosf(th, &sn, &cs);
    twFr[b-1] = cs; twFi[b-1] = -sn;
  }
  float twHr[4], twHi[4];
#pragma unroll
  for (int b = 0; b < 4; ++b) {
    float th = (float)(4 * rev + b) * 0.01227184630308513f; // 2pi/512
    float sn, cs; sincosf(th, &sn, &cs);
    twHr[b] = cs; twHi[b] = sn;
  }

  // ---- load x: float4 (n, d0..d0+3) -> stage[seq][n]; zero lambda ----
  {
    const float4* x4 = (const float4*)x;
    float4 va = x4[base4 + tid * 32];
    float4 vb = x4[base4 + (tid + 256) * 32];
    stage[tid]        = va.x; stage[512 + tid]        = va.y;
    stage[1024 + tid] = va.z; stage[1536 + tid]       = va.w;
    stage[tid + 256]        = vb.x; stage[512 + tid + 256]  = vb.y;
    stage[1024 + tid + 256] = vb.z; stage[1536 + tid + 256] = vb.w;
#pragma unroll
    for (int j = 0; j < 8; ++j) ldsLam[tid * 8 + j] = 0.0f;
  }
  __syncthreads();

  // ---- initial FFT input straight from LDS (x stays resident in stage) ----
  f2 z[4];
#pragma unroll
  for (int a = 0; a < 4; ++a) z[a] = stg2[64 * a + lane];
  fft256_fwd(z, twFr, twFi, Wr, Wi, lane);
  f2 X[4];
  float X256;
  {
    f2 P[4];
    P[0] = shfl2(z[0], pl0);
#pragma unroll
    for (int b = 1; b < 4; ++b) P[b] = shfl2(z[4 - b], plx);
    X256 = __shfl(z[0].x - z[0].y, 0, 64);
#pragma unroll
    for (int b = 0; b < 4; ++b) {
      f2 cP = conjf2(P[b]);
      f2 E = 0.5f * (z[b] + cP);
      f2 O = 0.5f * cmulni(z[b] - cP);
      X[b] = E + cmulc(O, twHr[b], twHi[b]);
    }
  }

  f2 U0[4], U1[4], lam[4];
#pragma unroll
  for (int b = 0; b < 4; ++b) {
    U0[b] = (f2){0.0f, 0.0f}; U1[b] = (f2){0.0f, 0.0f};
    lam[b] = (f2){0.0f, 0.0f};
  }
  float U0_256 = 0.0f, U1_256 = 0.0f;
  float om0 = 0.0f, om1 = 0.0f;

  const int psiE = 256 * (lane & 1) + (lane >> 1);   // lambda write base

#pragma unroll 1
  for (int it = 0; it < 50; ++it) {
    // lambda reads (psi layout): lam1[b]=lam[k+256], lam2[b]=lam[256-k]
    float lam1[4], lam2[4];
#pragma unroll
    for (int b = 0; b < 4; ++b) lam1[b] = lamLds[128 * b + 64 + rev];
    lam2[0] = lamLds[64 - rev];
#pragma unroll
    for (int b = 1; b < 4; ++b) lam2[b] = lamLds[128 * (4 - b) + 63 - rev];
    float lam0 = lamLds[0];

    mode_update4(X, U1, U0, lam1, lam2, om0, f0);
    {
      float dm = 0.5f + om0;
      float gg = __builtin_amdgcn_rcpf(fmaf(1600.0f * dm, dm, 1.0f));
      U0_256 = (X256 - U1_256 + 0.5f * lam0) * gg;
    }
    mode_update4(X, U0, U1, lam1, lam2, om1, f0);
    {
      float dm = 0.5f + om1;
      float gg = __builtin_amdgcn_rcpf(fmaf(1600.0f * dm, dm, 1.0f));
      U1_256 = (X256 - U0_256 + 0.5f * lam0) * gg;
    }

    // omega: all stored bins are positive freqs (packed (num,den) pairs)
    f2 s0 = (f2){0.0f, 0.0f}, s1 = (f2){0.0f, 0.0f};
#pragma unroll
    for (int b = 0; b < 4; ++b) {
      float f = f0 + (float)b * (1.0f / 512.0f);
      float p0 = fmaf(U0[b].x, U0[b].x, U0[b].y * U0[b].y);
      float p1 = fmaf(U1[b].x, U1[b].x, U1[b].y * U1[b].y);
      s0 = s0 + (f2){f * p0, p0};
      s1 = s1 + (f2){f * p1, p1};
    }
#pragma unroll
    for (int off = 32; off >= 1; off >>= 1) {
      s0 = s0 + shflx2(s0, off);
      s1 = s1 + shflx2(s1, off);
    }
    om0 = s0.x / (s0.y + 1e-7f);
    om1 = s1.x / (s1.y + 1e-7f);

    if (it < 49) {   // last iteration's lambda is never consumed
#pragma unroll
      for (int b = 0; b < 4; ++b) z[b] = U0[b] + U1[b];
      float S256 = U0_256 + U1_256;
      half_to_z(z, S256, twHr, twHi, lane, pl0, plx);
      ifft256(z, twFr, twFi, Wr, Wi, lane);
#pragma unroll
      for (int a = 0; a < 4; ++a) {
        f2 xa = stg2[64 * a + lane];               // x from LDS
        lam[a] = lam[a] + 0.001f * (xa - z[a] * (1.0f / 256.0f));
        lamLds[psiE + 32 * a]       = lam[a].x;
        lamLds[psiE + 32 * a + 128] = lam[a].y;
      }
      asm volatile("s_waitcnt lgkmcnt(0)" ::: "memory");
    }
  }

  // ---- final modes: half->z, ifft256, pack to stage, float4 stores ----
  float4* o4 = (float4*)out;
#pragma unroll
  for (int b = 0; b < 4; ++b) z[b] = U0[b];
  half_to_z(z, U0_256, twHr, twHi, lane, pl0, plx);
  ifft256(z, twFr, twFi, Wr, Wi, lane);
  __syncthreads();   // all waves done reading x from stage
#pragma unroll
  for (int a = 0; a < 4; ++a) stg2[64 * a + lane] = z[a] * (1.0f / 256.0f);
  __syncthreads();
#pragma unroll
  for (int r = 0; r < 2; ++r) {
    const int n = tid + r * 256;
    float4 v;
    v.x = stage[n]; v.y = stage[512 + n]; v.z = stage[1024 + n]; v.w = stage[1536 + n];
    o4[FIELD / 4 + base4 + n * 32] = v;
  }
  __syncthreads();
#pragma unroll
  for (int b = 0; b < 4; ++b) z[b] = U1[b];
  half_to_z(z, U1_256, twHr, twHi, lane, pl0, plx);
  ifft256(z, twFr, twFi, Wr, Wi, lane);
#pragma unroll
  for (int a = 0; a < 4; ++a) stg2[64 * a + lane] = z[a] * (1.0f / 256.0f);
  __syncthreads();
#pragma unroll
  for (int r = 0; r < 2; ++r) {
    const int n = tid + r * 256;
    float4 v;
    v.x = stage[n]; v.y = stage[512 + n]; v.z = stage[1024 + n]; v.w = stage[1536 + n];
    o4[2 * FIELD / 4 + base4 + n * 32] = v;
  }

  if (lane == 0) {
    out[g] = om0;            // staged in trend region (zeroed later)
    out[NSEQ + g] = om1;
  }
}

__global__ __launch_bounds__(128) void order_kernel(float* __restrict__ out) {
  const int bb = blockIdx.x;
  const int dd = threadIdx.x;
  float o0 = out[bb * 128 + dd];
  float o1 = out[NSEQ + bb * 128 + dd];
#pragma unroll
  for (int off = 32; off >= 1; off >>= 1) {
    o0 += __shfl_down(o0, off);
    o1 += __shfl_down(o1, off);
  }
  __shared__ float s0[2], s1[2];
  const int wv = dd >> 6;
  if ((dd & 63) == 0) { s0[wv] = o0; s1[wv] = o1; }
  __syncthreads();
  if (dd == 0) {
    const float a = s0[0] + s0[1];
    const float c = s1[0] + s1[1];
    out[2 * NSEQ + bb] = (a > c) ? 1.0f : 0.0f;
  }
}

__global__ __launch_bounds__(256) void swap_kernel(float* __restrict__ out) {
  const int idx = blockIdx.x * 256 + threadIdx.x;
  const int bb = idx >> 16;
  const float flag = out[2 * NSEQ + bb];
  if (flag > 0.5f) {
    const float p = out[FIELD + idx];
    const float r = out[2 * FIELD + idx];
    out[FIELD + idx] = r;
    out[2 * FIELD + idx] = p;
  }
}

extern "C" void kernel_launch(void* const* d_in, const int* in_sizes, int n_in,
                              void* d_out, int out_size, void* d_ws, size_t ws_size,
                              hipStream_t stream) {
  (void)in_sizes; (void)n_in; (void)d_ws; (void)ws_size; (void)out_size;
  const float* x = (const float*)d_in[0];
  float* out = (float*)d_out;
  vmd_kernel<<<NSEQ / 4, 256, 0, stream>>>(x, out);
  order_kernel<<<32, 128, 0, stream>>>(out);
  swap_kernel<<<FIELD / 256, 256, 0, stream>>>(out);
  hipMemsetAsync(out, 0, (size_t)FIELD * sizeof(float), stream);
}